// Round 12
// baseline (509.523 us; speedup 1.0000x reference)
//
#include <hip/hip_runtime.h>
#include <hip/hip_fp16.h>

#define FEAT 128
#define BSH 8              // 256 nodes per bucket
#define BSZ 256
#define NBMAX 400
#define ABLK 4096          // edges per pass-A block
#define CAP 6144           // tmp region capacity per bucket (mean 4092, >30 sigma)

typedef _Float16 half_t;
typedef _Float16 half4 __attribute__((ext_vector_type(4)));
typedef _Float16 half8 __attribute__((ext_vector_type(8)));
typedef float float4v __attribute__((ext_vector_type(4)));

// ---------------- bucket cursor init: fixed regions ----------------
__global__ void binit_kernel(int* __restrict__ gcur, int NB) {
    int b = blockIdx.x * blockDim.x + threadIdx.x;
    if (b < NB) gcur[b * 16] = b * CAP;
}

// ---------------- pass A: LDS-aggregated bucket scatter of raw {r,c} ----------------
__global__ __launch_bounds__(256) void bucketA_kernel(const int* __restrict__ row,
                                                      const int* __restrict__ col,
                                                      int* __restrict__ gcur,
                                                      long long* __restrict__ tmp,
                                                      int E, int NB) {
    __shared__ int hist[NBMAX];
    __shared__ int gbase[NBMAX];
    int t = threadIdx.x;
    int base = blockIdx.x * ABLK;
    for (int i = t; i < NB; i += 256) hist[i] = 0;
    __syncthreads();
    int r[16], c[16];
#pragma unroll
    for (int j = 0; j < 16; ++j) {
        int e = base + j * 256 + t;
        if (e < E) {
            r[j] = __builtin_nontemporal_load(row + e);
            c[j] = __builtin_nontemporal_load(col + e);
            atomicAdd(&hist[c[j] >> BSH], 1);
        } else c[j] = -1;
    }
    __syncthreads();
    for (int b = t; b < NB; b += 256) {
        int cnt = hist[b];
        if (cnt > 0) gbase[b] = atomicAdd(&gcur[b * 16], cnt);
    }
    __syncthreads();
    for (int i = t; i < NB; i += 256) hist[i] = 0;   // reuse as local cursor
    __syncthreads();
#pragma unroll
    for (int j = 0; j < 16; ++j) {
        if (c[j] >= 0) {
            int b = c[j] >> BSH;
            int lpos = atomicAdd(&hist[b], 1);
            long long pk = ((long long)(unsigned)c[j] << 32) | (unsigned)r[j];
            tmp[gbase[b] + lpos] = pk;
        }
    }
}

// ---------------- bucket-count scan ----------------
__global__ __launch_bounds__(512) void bscan_kernel(const int* __restrict__ gcur,
                                                    int* __restrict__ bbase,
                                                    int* __restrict__ offsN, int NB) {
    __shared__ int sd[512];
    int t = threadIdx.x;
    int v = (t < NB) ? (gcur[t * 16] - t * CAP) : 0;
    sd[t] = v;
    __syncthreads();
    for (int o = 1; o < 512; o <<= 1) {
        int u = (t >= o) ? sd[t - o] : 0;
        __syncthreads();
        sd[t] += u;
        __syncthreads();
    }
    if (t < NB) bbase[t] = sd[t] - v;    // exclusive
    if (t == NB - 1) *offsN = sd[t];     // offs[N] = E
}

// ---------------- bdeg: per-bucket degree count (LDS atomics) + offs + dinv ----------------
__global__ __launch_bounds__(256) void bdeg_kernel(const long long* __restrict__ tmp,
                                                   const int* __restrict__ gcur,
                                                   const int* __restrict__ bbase,
                                                   int* __restrict__ offs,
                                                   float* __restrict__ dinv, int N) {
    __shared__ int ldeg[BSZ];
    __shared__ int sums[BSZ];
    int b = blockIdx.x;
    int lo = b << BSH;
    int t = threadIdx.x;
    int cnt = gcur[b * 16] - b * CAP;
    ldeg[t] = 0;
    __syncthreads();
    const long long* reg = tmp + (size_t)b * CAP;
    for (int i = t; i < cnt; i += 256) {
        int c = (int)(__builtin_nontemporal_load(reg + i) >> 32);
        atomicAdd(&ldeg[c - lo], 1);
    }
    __syncthreads();
    int d = ldeg[t];
    sums[t] = d;
    __syncthreads();
    for (int o = 1; o < 256; o <<= 1) {
        int u = (t >= o) ? sums[t - o] : 0;
        __syncthreads();
        sums[t] += u;
        __syncthreads();
    }
    int node = lo + t;
    if (node < N) {
        offs[node] = bbase[b] + sums[t] - d;
        dinv[node] = (d > 0) ? rsqrtf((float)d) : 0.0f;
    }
}

// ---------------- bplace: per-bucket CSR fill (int src only) ----------------
__global__ __launch_bounds__(256) void bplace_kernel(const long long* __restrict__ tmp,
                                                     const int* __restrict__ gcur,
                                                     const int* __restrict__ offs,
                                                     int* __restrict__ csr, int N) {
    __shared__ int lcur[BSZ];
    int b = blockIdx.x;
    int lo = b << BSH;
    int hi = lo + BSZ;
    if (hi > N) hi = N;
    int t = threadIdx.x;
    int cnt = gcur[b * 16] - b * CAP;
    if (t < hi - lo) lcur[t] = offs[lo + t];
    __syncthreads();
    const long long* reg = tmp + (size_t)b * CAP;
    for (int i = t; i < cnt; i += 256) {
        long long pk = __builtin_nontemporal_load(reg + i);
        int r = (int)(pk & 0xffffffffLL);
        int c = (int)(pk >> 32);
        int pos = atomicAdd(&lcur[c - lo], 1);
        csr[pos] = r;
    }
}

// ---------------- zero row N of the state buffers ----------------
__global__ void zrow_kernel(half_t* a, half_t* b, half_t* c, half_t* d, half_t* e, int N) {
    int t = threadIdx.x;   // 128 threads
    size_t o = (size_t)N * FEAT + t;
    a[o] = (half_t)0.0f; b[o] = (half_t)0.0f; c[o] = (half_t)0.0f;
    d[o] = (half_t)0.0f; e[o] = (half_t)0.0f;
}

// ---------------- fused fp32->fp16 convert: x -> x16 AND g0=dinv*x16; W1; W2 ----------------
__global__ void f2h3_kernel(const float* __restrict__ a, half_t* __restrict__ ah,
                            half_t* __restrict__ gh, const float* __restrict__ dinv, int na4,
                            const float* __restrict__ b, half_t* __restrict__ bh, int nb4,
                            const float* __restrict__ c, half_t* __restrict__ ch, int nc4) {
    int i = blockIdx.x * blockDim.x + threadIdx.x;
    int j = i;
    if (j < na4) {
        float4 v = ((const float4*)a)[j];
        half4 o;
        o.x = (half_t)v.x; o.y = (half_t)v.y; o.z = (half_t)v.z; o.w = (half_t)v.w;
        ((half4*)ah)[j] = o;
        float dv = dinv[j >> 5];   // 32 float4 per 128-feature row
        half4 g;
        g.x = (half_t)(v.x * dv); g.y = (half_t)(v.y * dv);
        g.z = (half_t)(v.z * dv); g.w = (half_t)(v.w * dv);
        ((half4*)gh)[j] = g;
        return;
    }
    j -= na4;
    const float* src;
    half_t* dst;
    if (j < nb4) { src = b; dst = bh; }
    else if ((j -= nb4) < nc4) { src = c; dst = ch; }
    else return;
    float4 v = ((const float4*)src)[j];
    half4 o;
    o.x = (half_t)v.x; o.y = (half_t)v.y; o.z = (half_t)v.z; o.w = (half_t)v.w;
    ((half4*)dst)[j] = o;
}

// ---------------- propagation: state_out[v] = dinv[v]^2 * sum_e state_in[src_e] ----------------
// One wave per node; slots q=lane>>4, chunk p=lane&15. 8 independent 1KB gathers in flight
// (32 edges/iter). No per-edge weight (factorized norm). fp16 packed accumulation.
// Padding slots read zeroed row N.
__global__ __launch_bounds__(256) void prop16_kernel(const half_t* __restrict__ src,
                                                     half_t* __restrict__ dst,
                                                     const int* __restrict__ offs,
                                                     const int* __restrict__ csr,
                                                     const float* __restrict__ dinv, int N) {
    int v = blockIdx.x * 4 + (threadIdx.x >> 6);
    if (v >= N) return;
    int lane = threadIdx.x & 63;
    int q = lane >> 4;     // edge slot 0..3
    int p = lane & 15;     // 16B chunk within row
    int s0 = offs[v];
    int s1 = offs[v + 1];
    int last = s1 - 1;
    half8 accA = (half8)(half_t)0.0f;
    half8 accB = (half8)(half_t)0.0f;
    for (int base = s0; base < s1; base += 32) {
        int rr[8];
#pragma unroll
        for (int k = 0; k < 8; ++k) {
            int i = base + k * 4 + q;
            int ic = (i < s1) ? i : last;                    // in-bounds address
            int r = __builtin_nontemporal_load(csr + ic);
            rr[k] = (i < s1) ? r : N;                        // padding -> zero row
        }
        half8 g0 = *(const half8*)(src + (size_t)rr[0] * FEAT + p * 8);
        half8 g1 = *(const half8*)(src + (size_t)rr[1] * FEAT + p * 8);
        half8 g2 = *(const half8*)(src + (size_t)rr[2] * FEAT + p * 8);
        half8 g3 = *(const half8*)(src + (size_t)rr[3] * FEAT + p * 8);
        half8 g4 = *(const half8*)(src + (size_t)rr[4] * FEAT + p * 8);
        half8 g5 = *(const half8*)(src + (size_t)rr[5] * FEAT + p * 8);
        half8 g6 = *(const half8*)(src + (size_t)rr[6] * FEAT + p * 8);
        half8 g7 = *(const half8*)(src + (size_t)rr[7] * FEAT + p * 8);
        accA = accA + g0; accB = accB + g1;
        accA = accA + g2; accB = accB + g3;
        accA = accA + g4; accB = accB + g5;
        accA = accA + g6; accB = accB + g7;
    }
    half8 acc = accA + accB;
    union U { half8 h; int i[4]; };
    U u, o1;
    u.h = acc;
#pragma unroll
    for (int k = 0; k < 4; ++k) o1.i[k] = __shfl_xor(u.i[k], 32, 64);
    u.h = u.h + o1.h;
#pragma unroll
    for (int k = 0; k < 4; ++k) o1.i[k] = __shfl_xor(u.i[k], 16, 64);
    u.h = u.h + o1.h;
    if (lane < 16) {
        float d = dinv[v];
        float d2 = d * d;
        half8 outv;
#pragma unroll
        for (int j = 0; j < 8; ++j) outv[j] = (half_t)((float)u.h[j] * d2);
        *(half8*)(dst + (size_t)v * FEAT + p * 8) = outv;
    }
}

// ---------------- MFMA GEMM: out = concat(H0, s*H1, s*H2, s*H3) @ W.T + b ----------------
// H1..H3 are dinv-scaled states; per-row scale s[m]=sqrt(deg) recovers h. HALFOUT also
// emits gout = dinv*relu(out) for the next layer's propagation.
template <bool RELU, bool HALFOUT>
__global__ __launch_bounds__(256) void gemm16_kernel(const half_t* __restrict__ H0,
                                                     const half_t* __restrict__ H1,
                                                     const half_t* __restrict__ H2,
                                                     const half_t* __restrict__ H3,
                                                     const half_t* __restrict__ W,   // [128][512] fp16
                                                     const float* __restrict__ bias, // [128] fp32
                                                     const float* __restrict__ dinv,
                                                     half_t* __restrict__ out_h,
                                                     half_t* __restrict__ gout,
                                                     float* __restrict__ out_f, int N) {
    __shared__ half_t ws[128][40];   // [o][k-slice 32, pad->40]
    const int tid = threadIdx.x;
    const int lane = tid & 63;
    const int wid = tid >> 6;
    const int lr = lane & 15;        // m-in-tile
    const int lk = lane >> 4;        // 0..3
    const int m = blockIdx.x * 64 + wid * 16 + lr;
    const bool mok = (m < N);

    float dm = mok ? dinv[m] : 0.0f;
    half_t hs = (half_t)((dm > 0.0f) ? 1.0f / dm : 0.0f);   // sqrt(deg), 0 for deg-0

    float4v acc[8];
#pragma unroll
    for (int ct = 0; ct < 8; ++ct) acc[ct] = (float4v)0.0f;

    const half_t* Hs[4] = {H0, H1, H2, H3};
    const int wo = tid >> 1;
    const int wh = tid & 1;

#pragma unroll
    for (int b = 0; b < 4; ++b) {
        const half_t* __restrict__ H = Hs[b];
#pragma unroll
        for (int kt = 0; kt < 128; kt += 32) {
            half8 hfrag = (half8)(half_t)0.0f;
            if (mok) hfrag = *(const half8*)(H + (size_t)m * FEAT + kt + lk * 8);
            if (b > 0) hfrag = hfrag * hs;   // unscale state -> h
            const half8* wsrc = (const half8*)(W + (size_t)wo * 512 + b * 128 + kt + wh * 16);
            half8 w0 = wsrc[0];
            half8 w1 = wsrc[1];
            __syncthreads();
            *(half8*)&ws[wo][wh * 16 + 0] = w0;
            *(half8*)&ws[wo][wh * 16 + 8] = w1;
            __syncthreads();
#pragma unroll
            for (int ct = 0; ct < 8; ++ct) {
                half8 wfrag = *(const half8*)&ws[ct * 16 + lr][lk * 8];
                acc[ct] = __builtin_amdgcn_mfma_f32_16x16x32_f16(wfrag, hfrag, acc[ct], 0, 0, 0);
            }
        }
    }

    if (mok) {
        half_t hd = (half_t)dm;
#pragma unroll
        for (int ct = 0; ct < 8; ++ct) {
            int o = ct * 16 + lk * 4;
            float4 bv = *(const float4*)(bias + o);
            float r0 = acc[ct][0] + bv.x;
            float r1 = acc[ct][1] + bv.y;
            float r2 = acc[ct][2] + bv.z;
            float r3 = acc[ct][3] + bv.w;
            if (RELU) {
                r0 = fmaxf(r0, 0.0f); r1 = fmaxf(r1, 0.0f);
                r2 = fmaxf(r2, 0.0f); r3 = fmaxf(r3, 0.0f);
            }
            if (HALFOUT) {
                half4 hv;
                hv.x = (half_t)r0; hv.y = (half_t)r1; hv.z = (half_t)r2; hv.w = (half_t)r3;
                *(half4*)(out_h + (size_t)m * FEAT + o) = hv;
                half4 gv = hv * hd;
                *(half4*)(gout + (size_t)m * FEAT + o) = gv;
            } else {
                float4 fv;
                fv.x = r0; fv.y = r1; fv.z = r2; fv.w = r3;
                *(float4*)(out_f + (size_t)m * FEAT + o) = fv;
            }
        }
    }
}

extern "C" void kernel_launch(void* const* d_in, const int* in_sizes, int n_in,
                              void* d_out, int out_size, void* d_ws, size_t ws_size,
                              hipStream_t stream) {
    const float* x   = (const float*)d_in[0];
    const int*   ei  = (const int*)d_in[1];
    const float* W1  = (const float*)d_in[2];
    const float* b1  = (const float*)d_in[3];
    const float* W2  = (const float*)d_in[4];
    const float* b2  = (const float*)d_in[5];
    float* out = (float*)d_out;

    const int N = in_sizes[0] / FEAT;       // 100000
    const int E = in_sizes[1] / 2;          // 1600000
    const int* row = ei;
    const int* col = ei + E;
    const int NB = (N + BSZ - 1) / BSZ;     // buckets (391)

    // workspace carve
    size_t off = 0;
    auto carve = [&](size_t bytes) -> void* {
        void* p = (char*)d_ws + off;
        off += (bytes + 255) & ~(size_t)255;
        return p;
    };
    float*     dinv  = (float*)carve((size_t)N * 4);
    int*       offs  = (int*)carve((size_t)(N + 1) * 4);
    int*       bbase = (int*)carve((size_t)NB * 4);
    int*       gcur  = (int*)carve((size_t)NB * 16 * 4);   // padded cursors
    long long* tmp   = (long long*)carve((size_t)NB * CAP * 8);
    int*       csr   = (int*)carve((size_t)(E + 64) * 4);
    half_t*    x16   = (half_t*)carve((size_t)N * FEAT * 2);
    half_t*    g0    = (half_t*)carve((size_t)(N + 1) * FEAT * 2);
    half_t*    t1    = (half_t*)carve((size_t)(N + 1) * FEAT * 2);
    half_t*    t2    = (half_t*)carve((size_t)(N + 1) * FEAT * 2);
    half_t*    t3    = (half_t*)carve((size_t)(N + 1) * FEAT * 2);
    half_t*    hbuf  = (half_t*)carve((size_t)N * FEAT * 2);
    half_t*    ghbuf = (half_t*)carve((size_t)(N + 1) * FEAT * 2);
    half_t*    w1h   = (half_t*)carve((size_t)FEAT * 512 * 2);
    half_t*    w2h   = (half_t*)carve((size_t)FEAT * 512 * 2);

    const int tB = 256;
    const int gA = (E + ABLK - 1) / ABLK;       // pass-A blocks
    const int gP = (N + 3) / 4;                 // prop blocks (4 nodes/block, 1 wave/node)
    const int gG = (N + 63) / 64;               // gemm blocks (64 rows/block)
    const int xt4 = N * FEAT / 4;
    const int wt4 = FEAT * 512 / 4;
    const int cvt_total = xt4 + 2 * wt4;

    // ---- CSR build: bucket scatter -> scan -> LDS degree count -> place ----
    binit_kernel<<<(NB + tB - 1) / tB, tB, 0, stream>>>(gcur, NB);
    bucketA_kernel<<<gA, 256, 0, stream>>>(row, col, gcur, tmp, E, NB);
    bscan_kernel<<<1, 512, 0, stream>>>(gcur, bbase, offs + N, NB);
    bdeg_kernel<<<NB, 256, 0, stream>>>(tmp, gcur, bbase, offs, dinv, N);
    bplace_kernel<<<NB, 256, 0, stream>>>(tmp, gcur, offs, csr, N);

    // ---- zero row N of state buffers; fp16 conversions (+ g0 = dinv*x) ----
    zrow_kernel<<<1, 128, 0, stream>>>(g0, t1, t2, t3, ghbuf, N);
    f2h3_kernel<<<(cvt_total + tB - 1) / tB, tB, 0, stream>>>(x, x16, g0, dinv, xt4,
                                                              W1, w1h, wt4, W2, w2h, wt4);

    // ---- layer 1 ----
    prop16_kernel<<<gP, 256, 0, stream>>>(g0, t1, offs, csr, dinv, N);
    prop16_kernel<<<gP, 256, 0, stream>>>(t1, t2, offs, csr, dinv, N);
    prop16_kernel<<<gP, 256, 0, stream>>>(t2, t3, offs, csr, dinv, N);
    gemm16_kernel<true, true><<<gG, 256, 0, stream>>>(x16, t1, t2, t3, w1h, b1, dinv,
                                                      hbuf, ghbuf, nullptr, N);

    // ---- layer 2 ----
    prop16_kernel<<<gP, 256, 0, stream>>>(ghbuf, t1, offs, csr, dinv, N);
    prop16_kernel<<<gP, 256, 0, stream>>>(t1, t2, offs, csr, dinv, N);
    prop16_kernel<<<gP, 256, 0, stream>>>(t2, t3, offs, csr, dinv, N);
    gemm16_kernel<false, false><<<gG, 256, 0, stream>>>(hbuf, t1, t2, t3, w2h, b2, dinv,
                                                        nullptr, nullptr, out, N);
}